// Round 1
// baseline (1037.106 us; speedup 1.0000x reference)
//
#include <hip/hip_runtime.h>
#include <cstdint>
#include <cstddef>

typedef __attribute__((ext_vector_type(8))) short short8;
typedef __attribute__((ext_vector_type(4))) float floatx4;
typedef __attribute__((ext_vector_type(2))) unsigned int uint2v;

namespace {
constexpr int kBH = 32;    // B*H
constexpr int kS  = 2048;
constexpr int kD  = 128;
constexpr int kBQ = 64;    // q rows per block (16 per wave)
constexpr int kBK = 64;    // k cols per tile
constexpr int KST = 136;   // K tile LDS row stride (elems), 128+8 pad
constexpr int VST = 72;    // V^T tile LDS row stride (elems), 64+8 pad
constexpr int PST = 72;    // P tile LDS row stride (elems), 64+8 pad
}

__device__ __forceinline__ unsigned short f32_bf16(float f) {
    union { float f; unsigned u; } c; c.f = f;
    unsigned u = c.u;
    u += 0x7FFFu + ((u >> 16) & 1u);   // RNE
    return (unsigned short)(u >> 16);
}

__global__ __launch_bounds__(256, 2)
void fa_fwd_causal(const float* __restrict__ Qg, const float* __restrict__ Kg,
                   const float* __restrict__ Vg, float* __restrict__ Og) {
    const int bh    = blockIdx.y;
    const int qtile = (int)gridDim.x - 1 - (int)blockIdx.x;  // heavy tiles first
    const int t     = (int)threadIdx.x;
    const int wave  = t >> 6;
    const int lane  = t & 63;
    const int quad  = lane >> 4;
    const int l16   = lane & 15;

    __shared__ __align__(16) unsigned short kT[kBK * KST];     // [kj][d]
    __shared__ __align__(16) unsigned short vT[kD * VST];      // [d][kj] (transposed)
    __shared__ __align__(16) unsigned short pT[4 * 16 * PST];  // per-wave P tiles

    const float scale = 0.08838834764831845f;  // 1/sqrt(128)

    // ---- Q fragments (A-operand): rows qtile*64 + wave*16 + l16, pre-scaled ----
    const int qrow = qtile * kBQ + wave * 16 + l16;
    const float* qp = Qg + ((size_t)bh * kS + qrow) * kD;
    short8 qf[4];
#pragma unroll
    for (int ks = 0; ks < 4; ++ks) {
        const int d0 = ks * 32 + quad * 8;
        floatx4 a = *(const floatx4*)(qp + d0);
        floatx4 b = *(const floatx4*)(qp + d0 + 4);
        union { unsigned short us[8]; short8 v; } pk;
#pragma unroll
        for (int i = 0; i < 4; ++i) pk.us[i]     = f32_bf16(a[i] * scale);
#pragma unroll
        for (int i = 0; i < 4; ++i) pk.us[4 + i] = f32_bf16(b[i] * scale);
        qf[ks] = pk.v;
    }

    floatx4 oacc[8];
#pragma unroll
    for (int i = 0; i < 8; ++i) oacc[i] = (floatx4){0.f, 0.f, 0.f, 0.f};
    float mrow[4] = {-1e30f, -1e30f, -1e30f, -1e30f};
    float lrow[4] = {0.f, 0.f, 0.f, 0.f};

    // staging index helpers
    const int kRow8 = t >> 5;   // K staging: row-within-pass (0..7)
    const int kCol4 = t & 31;   // K staging: float4 column
    const int vD    = t & 127;  // V staging: d index (coalesced global reads)
    const int vR    = t >> 7;   // V staging: row-within-pass (0..1)

    const float* kBaseH = Kg + (size_t)bh * kS * kD;
    const float* vBaseH = Vg + (size_t)bh * kS * kD;

    const int nkt = qtile + 1;
    for (int kt = 0; kt < nkt; ++kt) {
        const int kj0 = kt * kBK;

        // ---- stage K tile [kj][d] as bf16 (float4 reads, 8B LDS writes) ----
        const float* kb = kBaseH + (size_t)kj0 * kD;
#pragma unroll
        for (int p = 0; p < 8; ++p) {
            const int row = p * 8 + kRow8;
            floatx4 x = *(const floatx4*)(kb + row * kD + kCol4 * 4);
            union { unsigned short us[4]; uint2v v; } w;
#pragma unroll
            for (int i = 0; i < 4; ++i) w.us[i] = f32_bf16(x[i]);
            *(uint2v*)&kT[row * KST + kCol4 * 4] = w.v;
        }

        // ---- stage V tile transposed [d][kj] (coalesced scalar reads) ----
        const float* vb = vBaseH + (size_t)kj0 * kD;
#pragma unroll
        for (int p = 0; p < 32; ++p) {
            const int row = p * 2 + vR;
            float x = vb[(size_t)row * kD + vD];
            vT[vD * VST + row] = f32_bf16(x);
        }
        __syncthreads();

        // ---- S = Q . K^T  (16x64 per wave) ----
        floatx4 sacc[4];
#pragma unroll
        for (int nt = 0; nt < 4; ++nt) {
            floatx4 acc = (floatx4){0.f, 0.f, 0.f, 0.f};
#pragma unroll
            for (int ks = 0; ks < 4; ++ks) {
                short8 kf = *(const short8*)&kT[(nt * 16 + l16) * KST + ks * 32 + quad * 8];
                acc = __builtin_amdgcn_mfma_f32_16x16x32_bf16(qf[ks], kf, acc, 0, 0, 0);
            }
            sacc[nt] = acc;
        }

        // ---- causal mask (only the diagonal tile can violate) ----
        if (kt == qtile) {
            const int rowl = wave * 16 + quad * 4;
#pragma unroll
            for (int nt = 0; nt < 4; ++nt) {
                const int col = nt * 16 + l16;
#pragma unroll
                for (int r = 0; r < 4; ++r)
                    if (col > rowl + r) sacc[nt][r] = -1e30f;
            }
        }

        // ---- online softmax update ----
        float rmax[4], rsum[4];
#pragma unroll
        for (int r = 0; r < 4; ++r)
            rmax[r] = fmaxf(fmaxf(sacc[0][r], sacc[1][r]), fmaxf(sacc[2][r], sacc[3][r]));
#pragma unroll
        for (int off = 1; off < 16; off <<= 1)
#pragma unroll
            for (int r = 0; r < 4; ++r)
                rmax[r] = fmaxf(rmax[r], __shfl_xor(rmax[r], off, 64));

        float alpha[4];
#pragma unroll
        for (int r = 0; r < 4; ++r) {
            const float mn = fmaxf(mrow[r], rmax[r]);
            alpha[r] = __expf(mrow[r] - mn);
            mrow[r] = mn;
        }
#pragma unroll
        for (int nt = 0; nt < 4; ++nt)
#pragma unroll
            for (int r = 0; r < 4; ++r)
                sacc[nt][r] = __expf(sacc[nt][r] - mrow[r]);
#pragma unroll
        for (int r = 0; r < 4; ++r)
            rsum[r] = (sacc[0][r] + sacc[1][r]) + (sacc[2][r] + sacc[3][r]);
#pragma unroll
        for (int off = 1; off < 16; off <<= 1)
#pragma unroll
            for (int r = 0; r < 4; ++r)
                rsum[r] += __shfl_xor(rsum[r], off, 64);
#pragma unroll
        for (int r = 0; r < 4; ++r)
            lrow[r] = lrow[r] * alpha[r] + rsum[r];
#pragma unroll
        for (int nd = 0; nd < 8; ++nd)
#pragma unroll
            for (int r = 0; r < 4; ++r)
                oacc[nd][r] *= alpha[r];

        // ---- P: C-layout -> LDS -> A-fragment layout (m120 pattern) ----
        unsigned short* pw = &pT[wave * 16 * PST];
#pragma unroll
        for (int nt = 0; nt < 4; ++nt)
#pragma unroll
            for (int r = 0; r < 4; ++r)
                pw[(quad * 4 + r) * PST + nt * 16 + l16] = f32_bf16(sacc[nt][r]);

        short8 pf[2];
#pragma unroll
        for (int ks = 0; ks < 2; ++ks)
            pf[ks] = *(const short8*)&pw[l16 * PST + ks * 32 + quad * 8];

        // ---- O += P . V ----
#pragma unroll
        for (int nd = 0; nd < 8; ++nd) {
            floatx4 acc = oacc[nd];
#pragma unroll
            for (int ks = 0; ks < 2; ++ks) {
                short8 vf = *(const short8*)&vT[(nd * 16 + l16) * VST + ks * 32 + quad * 8];
                acc = __builtin_amdgcn_mfma_f32_16x16x32_bf16(pf[ks], vf, acc, 0, 0, 0);
            }
            oacc[nd] = acc;
        }
        __syncthreads();
    }

    // ---- epilogue: O /= l, store fp32 ----
    const int orow0 = qtile * kBQ + wave * 16 + quad * 4;
    float inv[4];
#pragma unroll
    for (int r = 0; r < 4; ++r) inv[r] = 1.0f / lrow[r];
    float* ob = Og + ((size_t)bh * kS + orow0) * kD;
#pragma unroll
    for (int nd = 0; nd < 8; ++nd)
#pragma unroll
        for (int r = 0; r < 4; ++r)
            ob[(size_t)r * kD + nd * 16 + l16] = oacc[nd][r] * inv[r];
}

extern "C" void kernel_launch(void* const* d_in, const int* in_sizes, int n_in,
                              void* d_out, int out_size, void* d_ws, size_t ws_size,
                              hipStream_t stream) {
    (void)in_sizes; (void)n_in; (void)d_ws; (void)ws_size; (void)out_size;
    const float* q = (const float*)d_in[0];
    const float* k = (const float*)d_in[1];
    const float* v = (const float*)d_in[2];
    float* o = (float*)d_out;
    dim3 grid(kS / kBQ, kBH);
    fa_fwd_causal<<<grid, 256, 0, stream>>>(q, k, v, o);
}

// Round 2
// 268.798 us; speedup vs baseline: 3.8583x; 3.8583x over previous
//
#include <hip/hip_runtime.h>
#include <cstdint>
#include <cstddef>

typedef __attribute__((ext_vector_type(8))) short short8;
typedef __attribute__((ext_vector_type(4))) float floatx4;
typedef __attribute__((ext_vector_type(2))) unsigned int uint2v;

namespace {
constexpr int kBH  = 32;   // B*H
constexpr int kS   = 2048;
constexpr int kD   = 128;
constexpr int kBQ  = 64;   // q rows per tile (16 per wave); two tiles per block
constexpr int kBK  = 64;   // k cols per tile
constexpr int kNQT = kS / kBQ;  // 32 q-tiles
constexpr int KST  = 136;  // K tile LDS row stride (elems)
constexpr int VST  = 72;   // V^T tile LDS row stride (elems)
constexpr int PST  = 72;   // P tile LDS row stride (elems)
}

__device__ __forceinline__ unsigned short f32_bf16(float f) {
    union { float f; unsigned u; } c; c.f = f;
    unsigned u = c.u;
    u += 0x7FFFu + ((u >> 16) & 1u);   // RNE
    return (unsigned short)(u >> 16);
}

__device__ __forceinline__ unsigned pack_bf16x2(float lo, float hi) {
    return (unsigned)f32_bf16(lo) | ((unsigned)f32_bf16(hi) << 16);
}

struct TileState {
    short8  qf[4];
    floatx4 oacc[8];
    float   mrow[4];
    float   lrow[4];
};

// One (16-row q) x (64-col k) online-softmax step for one wave.
__device__ __forceinline__ void tile_step(
    TileState& ts, const unsigned short* kT, const unsigned short* vT,
    unsigned short* pw, int l16, int quad, int rowl, bool doMask)
{
    // S = Q . K^T
    floatx4 sacc[4];
#pragma unroll
    for (int nt = 0; nt < 4; ++nt) {
        floatx4 acc = (floatx4){0.f, 0.f, 0.f, 0.f};
#pragma unroll
        for (int ks = 0; ks < 4; ++ks) {
            short8 kf = *(const short8*)&kT[(nt * 16 + l16) * KST + ks * 32 + quad * 8];
            acc = __builtin_amdgcn_mfma_f32_16x16x32_bf16(ts.qf[ks], kf, acc, 0, 0, 0);
        }
        sacc[nt] = acc;
    }

    if (doMask) {
#pragma unroll
        for (int nt = 0; nt < 4; ++nt) {
            const int col = nt * 16 + l16;
#pragma unroll
            for (int r = 0; r < 4; ++r)
                if (col > rowl + r) sacc[nt][r] = -1e30f;
        }
    }

    // online softmax
    float rmax[4], rsum[4];
#pragma unroll
    for (int r = 0; r < 4; ++r)
        rmax[r] = fmaxf(fmaxf(sacc[0][r], sacc[1][r]), fmaxf(sacc[2][r], sacc[3][r]));
#pragma unroll
    for (int off = 1; off < 16; off <<= 1)
#pragma unroll
        for (int r = 0; r < 4; ++r)
            rmax[r] = fmaxf(rmax[r], __shfl_xor(rmax[r], off, 64));

    float alpha[4];
#pragma unroll
    for (int r = 0; r < 4; ++r) {
        const float mn = fmaxf(ts.mrow[r], rmax[r]);
        alpha[r] = __expf(ts.mrow[r] - mn);
        ts.mrow[r] = mn;
    }
#pragma unroll
    for (int nt = 0; nt < 4; ++nt)
#pragma unroll
        for (int r = 0; r < 4; ++r)
            sacc[nt][r] = __expf(sacc[nt][r] - ts.mrow[r]);
#pragma unroll
    for (int r = 0; r < 4; ++r)
        rsum[r] = (sacc[0][r] + sacc[1][r]) + (sacc[2][r] + sacc[3][r]);
#pragma unroll
    for (int off = 1; off < 16; off <<= 1)
#pragma unroll
        for (int r = 0; r < 4; ++r)
            rsum[r] += __shfl_xor(rsum[r], off, 64);
#pragma unroll
    for (int r = 0; r < 4; ++r)
        ts.lrow[r] = ts.lrow[r] * alpha[r] + rsum[r];
#pragma unroll
    for (int nd = 0; nd < 8; ++nd)
#pragma unroll
        for (int r = 0; r < 4; ++r)
            ts.oacc[nd][r] *= alpha[r];

    // P: C-layout -> LDS -> A-fragment layout
#pragma unroll
    for (int nt = 0; nt < 4; ++nt)
#pragma unroll
        for (int r = 0; r < 4; ++r)
            pw[(quad * 4 + r) * PST + nt * 16 + l16] = f32_bf16(sacc[nt][r]);

    short8 pf[2];
#pragma unroll
    for (int ks = 0; ks < 2; ++ks)
        pf[ks] = *(const short8*)&pw[l16 * PST + ks * 32 + quad * 8];

    // O += P . V
#pragma unroll
    for (int nd = 0; nd < 8; ++nd) {
        floatx4 acc = ts.oacc[nd];
#pragma unroll
        for (int ks = 0; ks < 2; ++ks) {
            short8 vf = *(const short8*)&vT[(nd * 16 + l16) * VST + ks * 32 + quad * 8];
            acc = __builtin_amdgcn_mfma_f32_16x16x32_bf16(pf[ks], vf, acc, 0, 0, 0);
        }
        ts.oacc[nd] = acc;
    }
}

__global__ __launch_bounds__(256, 2)
void fa_fwd_causal(const float* __restrict__ Qg, const float* __restrict__ Kg,
                   const float* __restrict__ Vg, float* __restrict__ Og) {
    const int bh = blockIdx.y;
    const int qA = blockIdx.x;            // small q-tile (0..15)
    const int qB = kNQT - 1 - qA;         // large q-tile (16..31)
    const int t    = (int)threadIdx.x;
    const int wave = t >> 6;
    const int lane = t & 63;
    const int quad = lane >> 4;
    const int l16  = lane & 15;
    const int rowl = wave * 16 + quad * 4;

    __shared__ __align__(16) unsigned short kT[kBK * KST];
    __shared__ __align__(16) unsigned short vT[kD * VST];
    __shared__ __align__(16) unsigned short pT[4 * 16 * PST];
    unsigned short* pw = &pT[wave * 16 * PST];

    const float scale = 0.08838834764831845f;  // 1/sqrt(128)

    // Q fragments for both tiles, pre-scaled
    TileState A, B;
#pragma unroll
    for (int i = 0; i < 8; ++i) { A.oacc[i] = (floatx4){0,0,0,0}; B.oacc[i] = (floatx4){0,0,0,0}; }
#pragma unroll
    for (int r = 0; r < 4; ++r) { A.mrow[r] = -1e30f; A.lrow[r] = 0.f; B.mrow[r] = -1e30f; B.lrow[r] = 0.f; }

    {
        const float* qpA = Qg + ((size_t)bh * kS + qA * kBQ + wave * 16 + l16) * kD;
        const float* qpB = Qg + ((size_t)bh * kS + qB * kBQ + wave * 16 + l16) * kD;
#pragma unroll
        for (int ks = 0; ks < 4; ++ks) {
            const int d0 = ks * 32 + quad * 8;
            floatx4 a0 = *(const floatx4*)(qpA + d0);
            floatx4 a1 = *(const floatx4*)(qpA + d0 + 4);
            floatx4 b0 = *(const floatx4*)(qpB + d0);
            floatx4 b1 = *(const floatx4*)(qpB + d0 + 4);
            union { unsigned short us[8]; short8 v; } pa, pb;
#pragma unroll
            for (int i = 0; i < 4; ++i) {
                pa.us[i]     = f32_bf16(a0[i] * scale);
                pa.us[4 + i] = f32_bf16(a1[i] * scale);
                pb.us[i]     = f32_bf16(b0[i] * scale);
                pb.us[4 + i] = f32_bf16(b1[i] * scale);
            }
            A.qf[ks] = pa.v;
            B.qf[ks] = pb.v;
        }
    }

    // staging index helpers
    const int kRow8 = t >> 5;   // K: row-within-pass (0..7)
    const int kCol4 = t & 31;   // K: float4 column
    const int vD    = t & 127;  // V: d index
    const int vR2   = t >> 7;   // V: pair-group (0..1)

    const float* kBaseH = Kg + (size_t)bh * kS * kD;
    const float* vBaseH = Vg + (size_t)bh * kS * kD;

    // prefetch registers
    floatx4 kpre[8];
    float   vpreL[16], vpreH[16];

    auto issue_kv_loads = [&](int kt) {
        const float* kb = kBaseH + (size_t)(kt * kBK) * kD;
        const float* vb = vBaseH + (size_t)(kt * kBK) * kD;
#pragma unroll
        for (int p = 0; p < 8; ++p)
            kpre[p] = *(const floatx4*)(kb + (size_t)(p * 8 + kRow8) * kD + kCol4 * 4);
#pragma unroll
        for (int p = 0; p < 16; ++p) {
            const int j = p * 2 + vR2;          // row pair 0..31
            vpreL[p] = vb[(size_t)(2 * j) * kD + vD];
            vpreH[p] = vb[(size_t)(2 * j + 1) * kD + vD];
        }
    };

    auto store_kv = [&]() {
#pragma unroll
        for (int p = 0; p < 8; ++p) {
            union { unsigned short us[4]; uint2v v; } w;
#pragma unroll
            for (int i = 0; i < 4; ++i) w.us[i] = f32_bf16(kpre[p][i]);
            *(uint2v*)&kT[(p * 8 + kRow8) * KST + kCol4 * 4] = w.v;
        }
#pragma unroll
        for (int p = 0; p < 16; ++p) {
            const int j = p * 2 + vR2;
            *(unsigned*)&vT[vD * VST + 2 * j] = pack_bf16x2(vpreL[p], vpreH[p]);
        }
    };

    const int last = qB;   // iterate kt = 0..qB
    issue_kv_loads(0);
    store_kv();
    __syncthreads();

    for (int kt = 0; kt <= last; ++kt) {
        if (kt < last) issue_kv_loads(kt + 1);   // in flight during compute

        if (kt <= qA) tile_step(A, kT, vT, pw, l16, quad, rowl, kt == qA);
        tile_step(B, kT, vT, pw, l16, quad, rowl, kt == last);

        __syncthreads();                          // all waves done reading LDS
        if (kt < last) {
            store_kv();                           // write tile kt+1
            __syncthreads();
        }
    }

    // epilogue: O /= l, store fp32 for both tiles
#pragma unroll
    for (int tile = 0; tile < 2; ++tile) {
        TileState& ts = tile ? B : A;
        const int qt = tile ? qB : qA;
        float inv[4];
#pragma unroll
        for (int r = 0; r < 4; ++r) inv[r] = 1.0f / ts.lrow[r];
        float* ob = Og + ((size_t)bh * kS + qt * kBQ + wave * 16 + quad * 4) * kD;
#pragma unroll
        for (int nd = 0; nd < 8; ++nd)
#pragma unroll
            for (int r = 0; r < 4; ++r)
                ob[(size_t)r * kD + nd * 16 + l16] = ts.oacc[nd][r] * inv[r];
    }
}

extern "C" void kernel_launch(void* const* d_in, const int* in_sizes, int n_in,
                              void* d_out, int out_size, void* d_ws, size_t ws_size,
                              hipStream_t stream) {
    (void)in_sizes; (void)n_in; (void)d_ws; (void)ws_size; (void)out_size;
    const float* q = (const float*)d_in[0];
    const float* k = (const float*)d_in[1];
    const float* v = (const float*)d_in[2];
    float* o = (float*)d_out;
    dim3 grid(kNQT / 2, kBH);   // 16 balanced q-tile pairs x 32 bh
    fa_fwd_causal<<<grid, 256, 0, stream>>>(q, k, v, o);
}